// Round 1
// baseline (142.026 us; speedup 1.0000x reference)
//
#include <hip/hip_runtime.h>
#include <math.h>

#define BS   4
#define V    4096
#define NB   50
#define IC   64
#define OC   64
#define SUP  4
#define WCOL ((SUP + 1) * OC)   // 320

// ---------------------------------------------------------------------------
// Kernel 1: feature_out = feature_map @ weights + bias, stored split:
//   fo_c[row*64 + c]            = feature_out[row][c]            (center)
//   fo_s[(row*64 + c)*4 + s]    = feature_out[row][64 + s*64+c]  (support,
//                                  transposed so each lane gathers a float4)
// ---------------------------------------------------------------------------
__global__ __launch_bounds__(WCOL) void feat_kernel(
    const float* __restrict__ fm,    // (BS*V, 64)
    const float* __restrict__ W,     // (64, 320)
    const float* __restrict__ bias,  // (320,)
    float* __restrict__ fo_c,        // (BS*V, 64)
    float* __restrict__ fo_s)        // (BS*V, 64, 4)
{
    const int row = blockIdx.x;
    const int k   = threadIdx.x;     // 0..319

    __shared__ float fm_s[IC];
    if (k < IC) fm_s[k] = fm[row * IC + k];
    __syncthreads();

    float acc = bias[k];
#pragma unroll
    for (int kk = 0; kk < IC; ++kk)
        acc = fmaf(fm_s[kk], W[kk * WCOL + k], acc);

    if (k < OC) {
        fo_c[row * OC + k] = acc;
    } else {
        const int kk = k - OC;
        const int s  = kk >> 6;      // 0..3
        const int c  = kk & 63;
        fo_s[(row * OC + c) * SUP + s] = acc;
    }
}

// ---------------------------------------------------------------------------
// Kernel 2: per output row (b,i), one wave (64 lanes), lane = channel c.
//   acc[c] = sum_j sum_s relu(d_j . sdn[:, s*64+c]) * fo_s[idx_j][c][s] * w_j
//   out[row][c] = fo_c[row][c] + acc[c]
// ---------------------------------------------------------------------------
__global__ __launch_bounds__(64) void conv_kernel(
    const int*   __restrict__ nidx,   // (BS, V, 50)
    const float* __restrict__ verts,  // (BS, V, 3)
    const float* __restrict__ nval,   // (BS, V, 50)
    const float* __restrict__ dirs,   // (3, 256)
    const float* __restrict__ fo_c,   // (BS*V, 64)
    const float* __restrict__ fo_s,   // (BS*V, 64, 4)
    float* __restrict__ out)          // (BS*V, 64)
{
    // XCD swizzle: 8 XCDs, 16384 blocks -> row = (bid%8)*2048 + bid/8.
    // Each batch (4096 rows, 4MB support slice) maps to 2 XCDs -> L2-resident.
    const int bid = blockIdx.x;
    const int row = ((bid & 7) << 11) + (bid >> 3);   // bijection on 16384
    const int b   = row >> 12;                        // row / V
    const int c   = threadIdx.x;                      // 0..63  (channel)

    // --- per-lane: load + normalize this lane's 4 direction columns -------
    float s0[SUP], s1[SUP], s2[SUP];
#pragma unroll
    for (int s = 0; s < SUP; ++s) {
        const int col = s * 64 + c;
        float d0 = dirs[0 * 256 + col];
        float d1 = dirs[1 * 256 + col];
        float d2 = dirs[2 * 256 + col];
        float inv = 1.0f / fmaxf(sqrtf(d0 * d0 + d1 * d1 + d2 * d2), 1e-12f);
        s0[s] = d0 * inv; s1[s] = d1 * inv; s2[s] = d2 * inv;
    }

    __shared__ float w_lds[NB];
    __shared__ float d_lds[NB][3];
    __shared__ int   i_lds[NB];

    // --- neighbor_value row normalize (wave reduction over 64 lanes) -----
    float nv = (c < NB) ? nval[row * NB + c] : 0.0f;
    float ss = nv * nv;
#pragma unroll
    for (int off = 32; off > 0; off >>= 1) ss += __shfl_xor(ss, off);
    const float inv1 = 1.0f / fmaxf(sqrtf(ss), 1e-12f);
    if (c < NB) w_lds[c] = nv * inv1;

    // --- neighbor index + normalized direction vector ---------------------
    if (c < NB) {
        const int idx = nidx[row * NB + c];
        i_lds[c] = idx;
        const float* vn = &verts[(b * V + idx) * 3];
        const float* vc = &verts[row * 3];
        float dx = vn[0] - vc[0];
        float dy = vn[1] - vc[1];
        float dz = vn[2] - vc[2];
        float inv = 1.0f / fmaxf(sqrtf(dx * dx + dy * dy + dz * dz), 1e-12f);
        d_lds[c][0] = dx * inv;
        d_lds[c][1] = dy * inv;
        d_lds[c][2] = dz * inv;
    }
    __syncthreads();

    // --- main gather + accumulate loop ------------------------------------
    float acc = 0.0f;
#pragma unroll 2
    for (int j = 0; j < NB; ++j) {
        const float dx = d_lds[j][0];
        const float dy = d_lds[j][1];
        const float dz = d_lds[j][2];
        const float wj = w_lds[j];
        const int  idx = i_lds[j];
        const float4 f = *reinterpret_cast<const float4*>(
            &fo_s[((b * V + idx) * OC + c) * SUP]);

        float t0 = fmaxf(fmaf(dx, s0[0], fmaf(dy, s1[0], dz * s2[0])), 0.0f);
        float t1 = fmaxf(fmaf(dx, s0[1], fmaf(dy, s1[1], dz * s2[1])), 0.0f);
        float t2 = fmaxf(fmaf(dx, s0[2], fmaf(dy, s1[2], dz * s2[2])), 0.0f);
        float t3 = fmaxf(fmaf(dx, s0[3], fmaf(dy, s1[3], dz * s2[3])), 0.0f);

        float sum = fmaf(t0, f.x, fmaf(t1, f.y, fmaf(t2, f.z, t3 * f.w)));
        acc = fmaf(sum, wj, acc);
    }

    out[row * OC + c] = fo_c[row * OC + c] + acc;
}

// ---------------------------------------------------------------------------
extern "C" void kernel_launch(void* const* d_in, const int* in_sizes, int n_in,
                              void* d_out, int out_size, void* d_ws, size_t ws_size,
                              hipStream_t stream) {
    const int*   nidx  = (const int*)  d_in[0];
    const float* verts = (const float*)d_in[1];
    const float* fm    = (const float*)d_in[2];
    const float* nval  = (const float*)d_in[3];
    const float* W     = (const float*)d_in[4];
    const float* bias  = (const float*)d_in[5];
    const float* dirs  = (const float*)d_in[6];
    float*       out   = (float*)d_out;

    float* fo_c = (float*)d_ws;                 // 16384*64  floats = 4 MB
    float* fo_s = fo_c + (size_t)BS * V * OC;   // 16384*256 floats = 16 MB

    feat_kernel<<<BS * V, WCOL, 0, stream>>>(fm, W, bias, fo_c, fo_s);
    conv_kernel<<<BS * V, 64, 0, stream>>>(nidx, verts, nval, dirs,
                                           fo_c, fo_s, out);
}

// Round 2
// 83.934 us; speedup vs baseline: 1.6921x; 1.6921x over previous
//
#include <hip/hip_runtime.h>
#include <math.h>

#define BS   4
#define V    4096
#define NB   50
#define IC   64
#define OC   64
#define SUP  4
#define WCOL ((SUP + 1) * OC)   // 320
#define ROWS 16                 // rows per feat block

// ---------------------------------------------------------------------------
// Kernel 1: feature_out = feature_map @ weights + bias, stored split:
//   fo_c[row*64 + c]          = feature_out[row][c]             (center, f32)
//   fo_s[(row*64 + c)*4 + s]  = bf16(feature_out[row][64+s*64+c]) (support,
//                                transposed so each lane gathers a ushort4)
// Each thread k owns W[:,k] in 64 VGPRs (loaded once per block); fm values
// are block-uniform -> scalar (SGPR) broadcast loads. 4 rows in flight.
// ---------------------------------------------------------------------------
__global__ __launch_bounds__(WCOL) void feat_kernel(
    const float* __restrict__ fm,    // (BS*V, 64)
    const float* __restrict__ W,     // (64, 320)
    const float* __restrict__ bias,  // (320,)
    float* __restrict__ fo_c,        // (BS*V, 64) f32
    unsigned short* __restrict__ fo_s) // (BS*V, 64, 4) bf16
{
    const int row0 = blockIdx.x * ROWS;
    const int k    = threadIdx.x;    // 0..319

    float wreg[IC];
#pragma unroll
    for (int kk = 0; kk < IC; ++kk)
        wreg[kk] = W[kk * WCOL + k];

    const float bk = bias[k];
    const int  s   = (k - OC) >> 6;  // valid only for k >= 64
    const int  c   = (k - OC) & 63;

    for (int rb = 0; rb < ROWS; rb += 4) {
        const float* __restrict__ f0 = &fm[(size_t)(row0 + rb + 0) * IC];
        const float* __restrict__ f1 = &fm[(size_t)(row0 + rb + 1) * IC];
        const float* __restrict__ f2 = &fm[(size_t)(row0 + rb + 2) * IC];
        const float* __restrict__ f3 = &fm[(size_t)(row0 + rb + 3) * IC];

        float a0 = bk, a1 = bk, a2 = bk, a3 = bk;
#pragma unroll
        for (int kk = 0; kk < IC; ++kk) {
            const float w = wreg[kk];
            a0 = fmaf(f0[kk], w, a0);
            a1 = fmaf(f1[kk], w, a1);
            a2 = fmaf(f2[kk], w, a2);
            a3 = fmaf(f3[kk], w, a3);
        }

        float av[4] = {a0, a1, a2, a3};
#pragma unroll
        for (int i = 0; i < 4; ++i) {
            const int row = row0 + rb + i;
            if (k < OC) {
                fo_c[row * OC + k] = av[i];
            } else {
                unsigned u = __builtin_bit_cast(unsigned, av[i]);
                u += 0x7FFFu + ((u >> 16) & 1u);          // RNE to bf16
                fo_s[((row * OC + c) << 2) + s] = (unsigned short)(u >> 16);
            }
        }
    }
}

// ---------------------------------------------------------------------------
// Kernel 2: per output row (b,i), one wave (64 lanes), lane = channel c.
//   acc[c] = sum_j sum_s relu(d_j . sdn[:, s*64+c]) * fo_s[idx_j][c][s] * w_j
//   out[row][c] = fo_c[row][c] + acc[c]
// fo_s gathered as ushort4 (bf16, 8 B/lane).
// ---------------------------------------------------------------------------
__global__ __launch_bounds__(64) void conv_kernel(
    const int*   __restrict__ nidx,   // (BS, V, 50)
    const float* __restrict__ verts,  // (BS, V, 3)
    const float* __restrict__ nval,   // (BS, V, 50)
    const float* __restrict__ dirs,   // (3, 256)
    const float* __restrict__ fo_c,   // (BS*V, 64) f32
    const unsigned short* __restrict__ fo_s, // (BS*V, 64, 4) bf16
    float* __restrict__ out)          // (BS*V, 64)
{
    // XCD swizzle: 8 XCDs, 16384 blocks -> row = (bid%8)*2048 + bid/8.
    // Each batch's support slice is now 2 MB -> L2-resident on its XCD pair.
    const int bid = blockIdx.x;
    const int row = ((bid & 7) << 11) + (bid >> 3);   // bijection on 16384
    const int b   = row >> 12;                        // row / V
    const int c   = threadIdx.x;                      // 0..63  (channel)

    // --- per-lane: load + normalize this lane's 4 direction columns -------
    float s0[SUP], s1[SUP], s2[SUP];
#pragma unroll
    for (int s = 0; s < SUP; ++s) {
        const int col = s * 64 + c;
        float d0 = dirs[0 * 256 + col];
        float d1 = dirs[1 * 256 + col];
        float d2 = dirs[2 * 256 + col];
        float inv = 1.0f / fmaxf(sqrtf(d0 * d0 + d1 * d1 + d2 * d2), 1e-12f);
        s0[s] = d0 * inv; s1[s] = d1 * inv; s2[s] = d2 * inv;
    }

    __shared__ float w_lds[NB];
    __shared__ float d_lds[NB][3];
    __shared__ int   i_lds[NB];

    // --- neighbor_value row normalize (wave reduction over 64 lanes) -----
    float nv = (c < NB) ? nval[row * NB + c] : 0.0f;
    float ss = nv * nv;
#pragma unroll
    for (int off = 32; off > 0; off >>= 1) ss += __shfl_xor(ss, off);
    const float inv1 = 1.0f / fmaxf(sqrtf(ss), 1e-12f);
    if (c < NB) w_lds[c] = nv * inv1;

    // --- neighbor index + normalized direction vector ---------------------
    if (c < NB) {
        const int idx = nidx[row * NB + c];
        i_lds[c] = idx;
        const float* vn = &verts[(b * V + idx) * 3];
        const float* vc = &verts[row * 3];
        float dx = vn[0] - vc[0];
        float dy = vn[1] - vc[1];
        float dz = vn[2] - vc[2];
        float inv = 1.0f / fmaxf(sqrtf(dx * dx + dy * dy + dz * dz), 1e-12f);
        d_lds[c][0] = dx * inv;
        d_lds[c][1] = dy * inv;
        d_lds[c][2] = dz * inv;
    }
    __syncthreads();

    // --- main gather + accumulate loop ------------------------------------
    float acc = 0.0f;
#pragma unroll 2
    for (int j = 0; j < NB; ++j) {
        const float dx = d_lds[j][0];
        const float dy = d_lds[j][1];
        const float dz = d_lds[j][2];
        const float wj = w_lds[j];
        const int  idx = i_lds[j];
        const ushort4 f = *reinterpret_cast<const ushort4*>(
            &fo_s[(((size_t)(b * V + idx) * OC + c) << 2)]);

        const float fx = __builtin_bit_cast(float, (unsigned)f.x << 16);
        const float fy = __builtin_bit_cast(float, (unsigned)f.y << 16);
        const float fz = __builtin_bit_cast(float, (unsigned)f.z << 16);
        const float fw = __builtin_bit_cast(float, (unsigned)f.w << 16);

        float t0 = fmaxf(fmaf(dx, s0[0], fmaf(dy, s1[0], dz * s2[0])), 0.0f);
        float t1 = fmaxf(fmaf(dx, s0[1], fmaf(dy, s1[1], dz * s2[1])), 0.0f);
        float t2 = fmaxf(fmaf(dx, s0[2], fmaf(dy, s1[2], dz * s2[2])), 0.0f);
        float t3 = fmaxf(fmaf(dx, s0[3], fmaf(dy, s1[3], dz * s2[3])), 0.0f);

        float sum = fmaf(t0, fx, fmaf(t1, fy, fmaf(t2, fz, t3 * fw)));
        acc = fmaf(sum, wj, acc);
    }

    out[row * OC + c] = fo_c[row * OC + c] + acc;
}

// ---------------------------------------------------------------------------
extern "C" void kernel_launch(void* const* d_in, const int* in_sizes, int n_in,
                              void* d_out, int out_size, void* d_ws, size_t ws_size,
                              hipStream_t stream) {
    const int*   nidx  = (const int*)  d_in[0];
    const float* verts = (const float*)d_in[1];
    const float* fm    = (const float*)d_in[2];
    const float* nval  = (const float*)d_in[3];
    const float* W     = (const float*)d_in[4];
    const float* bias  = (const float*)d_in[5];
    const float* dirs  = (const float*)d_in[6];
    float*       out   = (float*)d_out;

    float*          fo_c = (float*)d_ws;                       // 4 MB
    unsigned short* fo_s = (unsigned short*)(fo_c + (size_t)BS * V * OC); // 8 MB

    feat_kernel<<<(BS * V) / ROWS, WCOL, 0, stream>>>(fm, W, bias, fo_c, fo_s);
    conv_kernel<<<BS * V, 64, 0, stream>>>(nidx, verts, nval, dirs,
                                           fo_c, fo_s, out);
}

// Round 5
// 63.914 us; speedup vs baseline: 2.2221x; 1.3132x over previous
//
#include <hip/hip_runtime.h>
#include <math.h>

#define BS   4
#define V    4096
#define NB   50
#define IC   64
#define OC   64
#define SUP  4
#define WCOL 320
#define WT_STRIDE 72   // shorts; 144B row -> 2-way LDS bank aliasing (free)

typedef float f32x2 __attribute__((ext_vector_type(2)));
typedef float f32x4 __attribute__((ext_vector_type(4)));
typedef short s16x8 __attribute__((ext_vector_type(8)));

__device__ inline unsigned short bf16r(float f) {          // RNE f32->bf16
    unsigned u = __builtin_bit_cast(unsigned, f);
    u += 0x7FFFu + ((u >> 16) & 1u);
    return (unsigned short)(u >> 16);
}
__device__ inline f32x2 pk_mul(f32x2 a, f32x2 b) {
    f32x2 d; asm("v_pk_mul_f32 %0, %1, %2" : "=v"(d) : "v"(a), "v"(b)); return d;
}
__device__ inline f32x2 pk_fma(f32x2 a, f32x2 b, f32x2 c) {
    f32x2 d; asm("v_pk_fma_f32 %0, %1, %2, %3" : "=v"(d) : "v"(a), "v"(b), "v"(c)); return d;
}

// ---------------------------------------------------------------------------
// Kernel 1 (MFMA): feature_out = fm @ W + bias.
//   fo_c[row*64 + c]         = feature_out[row][c]              (f32)
//   fo_s[(row*64 + c)*4 + s] = bf16(feature_out[row][64+s*64+c])
// Block = 256 thr (4 waves), 64 rows/block. W staged bf16-transposed in LDS.
// mfma_f32_16x16x32_bf16 layouts: A lane l: row=l&15, k=(l>>4)*8+e;
// B lane l: col=l&15, k=(l>>4)*8+e; D lane l reg r: col=l&15, row=(l>>4)*4+r.
// ---------------------------------------------------------------------------
__global__ __launch_bounds__(256) void feat_kernel(
    const float* __restrict__ fm,    // (16384, 64)
    const float* __restrict__ W,     // (64, 320)
    const float* __restrict__ bias,  // (320,)
    float* __restrict__ fo_c,
    unsigned short* __restrict__ fo_s)
{
    __shared__ unsigned short wt[WCOL * WT_STRIDE];  // wt[col][k], 45 KB
    const int t = threadIdx.x;

    // stage W (f32 row-major) -> wt (bf16, [col][k], stride 72)
#pragma unroll
    for (int i = 0; i < 20; ++i) {
        const int idx4 = t + i * 256;        // 0..5119 float4s
        const int e    = idx4 * 4;
        const int k    = e / WCOL;
        const int col  = e - k * WCOL;       // multiple of 4
        const float4 v = reinterpret_cast<const float4*>(W)[idx4];
        wt[(col + 0) * WT_STRIDE + k] = bf16r(v.x);
        wt[(col + 1) * WT_STRIDE + k] = bf16r(v.y);
        wt[(col + 2) * WT_STRIDE + k] = bf16r(v.z);
        wt[(col + 3) * WT_STRIDE + k] = bf16r(v.w);
    }
    __syncthreads();

    const int w   = t >> 6;
    const int l   = t & 63;
    const int rlo = l & 15;          // A row within tile / B,D col within tile
    const int kg  = l >> 4;          // k group
    const int row = blockIdx.x * 64 + w * 16 + rlo;

    const float* fr = &fm[row * IC + kg * 8];
    s16x8 a0, a1;
#pragma unroll
    for (int e = 0; e < 8; ++e) {
        a0[e] = (short)bf16r(fr[e]);        // k = kg*8+e
        a1[e] = (short)bf16r(fr[32 + e]);   // k = 32+kg*8+e
    }

    const int drow0 = blockIdx.x * 64 + w * 16 + kg * 4;  // D rows
#pragma unroll
    for (int ct = 0; ct < 20; ++ct) {
        const int col = ct * 16 + rlo;
        const s16x8 b0 = *reinterpret_cast<const s16x8*>(&wt[col * WT_STRIDE + kg * 8]);
        const s16x8 b1 = *reinterpret_cast<const s16x8*>(&wt[col * WT_STRIDE + 32 + kg * 8]);
        f32x4 acc = {0.f, 0.f, 0.f, 0.f};
        acc = __builtin_amdgcn_mfma_f32_16x16x32_bf16(a0, b0, acc, 0, 0, 0);
        acc = __builtin_amdgcn_mfma_f32_16x16x32_bf16(a1, b1, acc, 0, 0, 0);
        const float bv = bias[col];
        if (ct < 4) {
#pragma unroll
            for (int r = 0; r < 4; ++r)
                fo_c[(drow0 + r) * OC + col] = acc[r] + bv;
        } else {
            const int cc = (col - OC) & 63;
            const int s  = (col - OC) >> 6;
#pragma unroll
            for (int r = 0; r < 4; ++r)
                fo_s[((drow0 + r) * OC + cc) * SUP + s] = bf16r(acc[r] + bv);
        }
    }
}

// ---------------------------------------------------------------------------
// Kernel 2: 4 rows per block (4 waves), lane = channel. Packed-pair math
// (v_pk_fma_f32), pre-duplicated {dx,dx} pairs in LDS, 10-deep gather
// double-buffer to hide L2 latency.
// ---------------------------------------------------------------------------
__global__ __launch_bounds__(256) void conv_kernel(
    const int*   __restrict__ nidx,   // (BS, V, 50)
    const float* __restrict__ verts,  // (BS, V, 3)
    const float* __restrict__ nval,   // (BS, V, 50)
    const float* __restrict__ dirs,   // (3, 256)
    const float* __restrict__ fo_c,   // (16384, 64) f32
    const unsigned short* __restrict__ fo_s, // (16384, 64, 4) bf16
    float* __restrict__ out)          // (16384, 64)
{
    const int bid = blockIdx.x;                     // 0..4095
    const int swz = ((bid & 7) << 9) + (bid >> 3);  // XCD bijection on 4096
    const int wv  = threadIdx.x >> 6;
    const int c   = threadIdx.x & 63;
    const int row = swz * 4 + wv;                   // blocks never cross batch
    const int b   = swz >> 10;                      // uniform per block

    __shared__ f32x2 ddw[4][NB][4];   // per-wave: {dx,dx},{dy,dy},{dz,dz},{w,w}
    __shared__ int   offj[4][NB];     // idx*512 byte offsets

    // per-lane normalized direction columns, packed for pk ops
    f32x2 cx01, cx23, cy01, cy23, cz01, cz23;
    {
        float sx[4], sy[4], sz[4];
#pragma unroll
        for (int s = 0; s < 4; ++s) {
            const int col = s * 64 + c;
            const float d0 = dirs[col], d1 = dirs[256 + col], d2 = dirs[512 + col];
            const float inv = 1.f / fmaxf(sqrtf(d0 * d0 + d1 * d1 + d2 * d2), 1e-12f);
            sx[s] = d0 * inv; sy[s] = d1 * inv; sz[s] = d2 * inv;
        }
        cx01 = (f32x2){sx[0], sx[1]}; cx23 = (f32x2){sx[2], sx[3]};
        cy01 = (f32x2){sy[0], sy[1]}; cy23 = (f32x2){sy[2], sy[3]};
        cz01 = (f32x2){sz[0], sz[1]}; cz23 = (f32x2){sz[2], sz[3]};
    }

    // neighbor_value normalize (wave reduction)
    const float nv = (c < NB) ? nval[row * NB + c] : 0.f;
    float ssum = nv * nv;
#pragma unroll
    for (int o = 32; o > 0; o >>= 1) ssum += __shfl_xor(ssum, o);
    const float wn = nv * (1.f / fmaxf(sqrtf(ssum), 1e-12f));

    if (c < NB) {
        const int idx = nidx[row * NB + c];
        offj[wv][c] = idx << 9;                     // *512 B
        const float* vn = &verts[(b * V + idx) * 3];
        const float* vc = &verts[row * 3];
        float dx = vn[0] - vc[0], dy = vn[1] - vc[1], dz = vn[2] - vc[2];
        const float inv = 1.f / fmaxf(sqrtf(dx * dx + dy * dy + dz * dz), 1e-12f);
        dx *= inv; dy *= inv; dz *= inv;
        ddw[wv][c][0] = (f32x2){dx, dx};
        ddw[wv][c][1] = (f32x2){dy, dy};
        ddw[wv][c][2] = (f32x2){dz, dz};
        ddw[wv][c][3] = (f32x2){wn, wn};
    }
    __syncthreads();

    const char* base = (const char*)fo_s + (size_t)b * (V * OC * SUP * 2);
    const int c8 = c << 3;
    f32x2 acc = {0.f, 0.f};
    uint2 fA[10], fB[10];

#define LOADB(buf, j0) _Pragma("unroll") \
    for (int jj = 0; jj < 10; ++jj) \
        buf[jj] = *reinterpret_cast<const uint2*>(base + offj[wv][(j0) + jj] + c8);

#define COMPB(buf, j0) _Pragma("unroll") \
    for (int jj = 0; jj < 10; ++jj) { \
        const int j = (j0) + jj; \
        const f32x2 xx = ddw[wv][j][0], yy = ddw[wv][j][1]; \
        const f32x2 zz = ddw[wv][j][2], ww = ddw[wv][j][3]; \
        f32x2 t01 = pk_fma(xx, cx01, pk_fma(yy, cy01, pk_mul(zz, cz01))); \
        f32x2 t23 = pk_fma(xx, cx23, pk_fma(yy, cy23, pk_mul(zz, cz23))); \
        t01.x = fmaxf(t01.x, 0.f); t01.y = fmaxf(t01.y, 0.f); \
        t23.x = fmaxf(t23.x, 0.f); t23.y = fmaxf(t23.y, 0.f); \
        f32x2 f01, f23; \
        f01.x = __builtin_bit_cast(float, buf[jj].x << 16); \
        f01.y = __builtin_bit_cast(float, buf[jj].x & 0xffff0000u); \
        f23.x = __builtin_bit_cast(float, buf[jj].y << 16); \
        f23.y = __builtin_bit_cast(float, buf[jj].y & 0xffff0000u); \
        f32x2 m = pk_mul(t01, f01); \
        m   = pk_fma(t23, f23, m); \
        acc = pk_fma(m, ww, acc); \
    }

    LOADB(fA, 0);
    LOADB(fB, 10); COMPB(fA, 0);
    LOADB(fA, 20); COMPB(fB, 10);
    LOADB(fB, 30); COMPB(fA, 20);
    LOADB(fA, 40); COMPB(fB, 30);
                   COMPB(fA, 40);
#undef LOADB
#undef COMPB

    out[row * OC + c] = fo_c[row * OC + c] + acc.x + acc.y;
}

// ---------------------------------------------------------------------------
extern "C" void kernel_launch(void* const* d_in, const int* in_sizes, int n_in,
                              void* d_out, int out_size, void* d_ws, size_t ws_size,
                              hipStream_t stream) {
    const int*   nidx  = (const int*)  d_in[0];
    const float* verts = (const float*)d_in[1];
    const float* fm    = (const float*)d_in[2];
    const float* nval  = (const float*)d_in[3];
    const float* W     = (const float*)d_in[4];
    const float* bias  = (const float*)d_in[5];
    const float* dirs  = (const float*)d_in[6];
    float*       out   = (float*)d_out;

    float*          fo_c = (float*)d_ws;                                   // 4 MB
    unsigned short* fo_s = (unsigned short*)(fo_c + (size_t)BS * V * OC);  // 8 MB

    feat_kernel<<<(BS * V) / 64, 256, 0, stream>>>(fm, W, bias, fo_c, fo_s);
    conv_kernel<<<(BS * V) / 4, 256, 0, stream>>>(nidx, verts, nval, dirs,
                                                  fo_c, fo_s, out);
}